// Round 1
// 254.335 us; speedup vs baseline: 1.0276x; 1.0276x over previous
//
#include <hip/hip_runtime.h>

// VQ-VAE quantizer: z [16,4096,64] f32, embedding [1024,64] f32.
// Outputs concatenated in d_out (float32): [0]=loss, [1..4194304]=z_q,
// [4194305..]=argmin indices (as float).
//
// Correctness-critical (verified absmax 0.0 previously): argmin mirrors numpy
// bitwise. d = fmaf(-2,dot,(zz+ee)); zz/ee use numpy's pairwise 8-accumulator
// tree with fp-contract OFF; strict < gives first-index tie-break; segments
// merged in ascending order. Loss: wave0 per-row sequential col sum + 64-lane
// shfl tree + one atomic/block (identical structure to verified kernel).
//
// R3 change: make zr[64] truly register-resident. Old version capped VGPRs at
// 85 (launch_bounds 512,6) -> compiler re-read the z row from LDS/AGPR inside
// the 128-code inner loop (VGPR_Count=40 proved zr was not in registers),
// costing ~56 extra issue-cycles/code + stalls (VALUBusy 37%). Now:
//   - __launch_bounds__(512,4): 128-VGPR budget, zr + 2-code e-buffer fit.
//   - lds_z removed (25.6KB -> 8.2KB LDS): each lane loads its row directly
//     from global (z still read exactly once; L1 absorbs the stride).
//   - epilogue distributed: every wave holds the same 64 rows in registers,
//     wave w stores columns [8w,8w+8) of z_q (compile-time guard, no dynamic
//     register indexing); wave0 does loss+idx exactly as before.

#define D 64
#define NE 1024
#define SEGS 8
#define CPS 128              // codes per segment = NE/SEGS
#define ROWS 64              // rows per block
#define TPB 512

__global__ __launch_bounds__(TPB, 4) void vq_kernel(const float* __restrict__ z,
                                                    const float* __restrict__ emb,
                                                    float* __restrict__ out_loss,
                                                    float* __restrict__ out_zq,
                                                    float* __restrict__ out_idx,
                                                    float loss_scale) {
    __shared__ float ee_lds[NE];
    __shared__ float smv[SEGS * ROWS];
    __shared__ int   smi[SEGS * ROWS];

    const int tid = threadIdx.x;
    const size_t blockRow = (size_t)blockIdx.x * ROWS;
    const int rrow = tid & (ROWS - 1);   // row within tile (same mapping in every wave)
    const int seg  = tid >> 6;           // wave id = codebook segment (0..7)

    // --- ee[j] = numpy-pairwise sum(e*e) for all 1024 codes (2 per thread).
    //     Must match np bitwise: 8 accumulators over stride-8 cols, contract off.
    {
#pragma clang fp contract(off)
#pragma unroll
        for (int cc = 0; cc < 2; ++cc) {
            const int j = tid + cc * TPB;
            const float4* e4 = (const float4*)(emb + ((size_t)j << 6));
            float4 a = e4[0], b = e4[1];
            float r[8];
            r[0] = a.x*a.x; r[1] = a.y*a.y; r[2] = a.z*a.z; r[3] = a.w*a.w;
            r[4] = b.x*b.x; r[5] = b.y*b.y; r[6] = b.z*b.z; r[7] = b.w*b.w;
#pragma unroll
            for (int g = 1; g < 8; ++g) {
                float4 c = e4[2*g], e = e4[2*g + 1];
                r[0] = r[0] + c.x*c.x; r[1] = r[1] + c.y*c.y;
                r[2] = r[2] + c.z*c.z; r[3] = r[3] + c.w*c.w;
                r[4] = r[4] + e.x*e.x; r[5] = r[5] + e.y*e.y;
                r[6] = r[6] + e.z*e.z; r[7] = r[7] + e.w*e.w;
            }
            ee_lds[j] = ((r[0]+r[1]) + (r[2]+r[3])) + ((r[4]+r[5]) + (r[6]+r[7]));
        }
    }

    // --- z row straight into registers (per-lane row; every wave loads the
    //     same 64-row tile, lane r <-> row r). z is read once from HBM; the
    //     256B-stride lane pattern is absorbed by L1 across the 16 loads.
    float zr[D];
    {
        const float4* zrow4 = (const float4*)(z + (blockRow + rrow) * D);
#pragma unroll
        for (int c = 0; c < 16; ++c) {
            float4 v = zrow4[c];
            zr[4*c+0] = v.x; zr[4*c+1] = v.y; zr[4*c+2] = v.z; zr[4*c+3] = v.w;
        }
    }

    // zz = numpy-pairwise sum(z*z), contract off.
    float zz;
    {
#pragma clang fp contract(off)
        float r[8];
#pragma unroll
        for (int jj = 0; jj < 8; ++jj) { float t = zr[jj] * zr[jj]; r[jj] = t; }
#pragma unroll
        for (int i = 8; i < 64; i += 8) {
#pragma unroll
            for (int jj = 0; jj < 8; ++jj) { float t = zr[i+jj] * zr[i+jj]; r[jj] = r[jj] + t; }
        }
        zz = ((r[0]+r[1]) + (r[2]+r[3])) + ((r[4]+r[5]) + (r[6]+r[7]));
    }

    __syncthreads();   // ee_lds ready

    // --- Scan this wave's codebook segment. j wave-uniform -> broadcast loads. ---
    float minv = __builtin_inff();
    int mini = 0;
    const int jbase = __builtin_amdgcn_readfirstlane(seg * CPS);
#pragma unroll 2
    for (int jj = 0; jj < CPS; ++jj) {
        const int j = jbase + jj;
        const float4* ew4 = (const float4*)(emb + ((size_t)j << 6));
        float p0 = 0.f, p1 = 0.f, p2 = 0.f, p3 = 0.f;
#pragma unroll
        for (int c = 0; c < 16; ++c) {
            float4 e4 = ew4[c];
            p0 = fmaf(zr[4*c+0], e4.x, p0);
            p1 = fmaf(zr[4*c+1], e4.y, p1);
            p2 = fmaf(zr[4*c+2], e4.z, p2);
            p3 = fmaf(zr[4*c+3], e4.w, p3);
        }
        float dot = (p0 + p1) + (p2 + p3);
        float t1 = zz + ee_lds[j];             // mirrors np (zz + ee) rounding
        float d = fmaf(-2.0f, dot, t1);        // == round(t1 - 2*dot)
        if (d < minv) { minv = d; mini = j; }  // strict < -> first index on tie
    }

    smv[seg * ROWS + rrow] = minv;
    smi[seg * ROWS + rrow] = mini;
    __syncthreads();

    // --- Epilogue: every wave redundantly merges row rrow (identical result),
    //     then wave `seg` stores columns [8*seg, 8*seg+8) of z_q. ---
    float best = __builtin_inff();
    int bi = 0;
#pragma unroll
    for (int s = 0; s < SEGS; ++s) {           // ascending seg = ascending j
        float v = smv[s * ROWS + rrow];
        if (v < best) { best = v; bi = smi[s * ROWS + rrow]; }
    }

    const float4* qe4 = (const float4*)(emb + ((size_t)bi << 6));
    float s = 0.f;
    float* orow = out_zq + (blockRow + rrow) * D;
#pragma unroll
    for (int c = 0; c < 16; ++c) {
        float4 q = qe4[c];
        float z0 = zr[4*c+0], z1 = zr[4*c+1], z2 = zr[4*c+2], z3 = zr[4*c+3];
        float d0 = q.x - z0, d1 = q.y - z1, d2 = q.z - z2, d3 = q.w - z3;
        s += d0*d0; s += d1*d1; s += d2*d2; s += d3*d3;
        if ((c >> 1) == seg) {                 // wave-uniform guard, no divergence
            // out_zq is d_out+1 (4B-aligned) -> dword stores.
            orow[4*c+0] = z0 + d0; orow[4*c+1] = z1 + d1;
            orow[4*c+2] = z2 + d2; orow[4*c+3] = z3 + d3;
        }
    }

    if (seg == 0) {                            // loss + idx: wave 0 only,
        out_idx[blockRow + rrow] = (float)bi;  // identical reduction structure
#pragma unroll                                 // to the verified kernel.
        for (int off = 32; off; off >>= 1) s += __shfl_down(s, off);
        if (tid == 0) atomicAdd(out_loss, s * loss_scale);
    }
}

extern "C" void kernel_launch(void* const* d_in, const int* in_sizes, int n_in,
                              void* d_out, int out_size, void* d_ws, size_t ws_size,
                              hipStream_t stream) {
    const float* z   = (const float*)d_in[0];
    const float* emb = (const float*)d_in[1];
    const int nz = in_sizes[0];          // 4194304
    const int N  = nz / D;               // 65536 rows

    float* out      = (float*)d_out;
    float* out_zq   = out + 1;
    float* out_idx  = out + 1 + (size_t)nz;

    const float loss_scale = 1.25f / (float)nz;

    hipMemsetAsync(out, 0, sizeof(float), stream);  // loss accumulator
    vq_kernel<<<N / ROWS, TPB, 0, stream>>>(z, emb, out, out_zq, out_idx, loss_scale);
}